// Round 8
// baseline (512.179 us; speedup 1.0000x reference)
//
#include <hip/hip_runtime.h>
#include <math.h>

#define H_ 128
#define W_ 128
#define C_ 64
#define O_ 64
#define B_ 8
#define K2_ 9
#define HWSZ (H_*W_)

typedef __attribute__((ext_vector_type(4))) float floatx4;

// ---------------------------------------------------------------------------
// Kernel T: transpose w (O,C,3,3) -> wt (K2, C, O): FMA phase reads weights
// contiguously in o at wave-uniform addresses (s_load_dwordx16).
// ---------------------------------------------------------------------------
__global__ __launch_bounds__(256) void transpose_w_k(const float* __restrict__ w,
                                                     float* __restrict__ wt) {
    int id = blockIdx.x * 256 + threadIdx.x;   // k*C*O + c*O + o
    if (id >= K2_ * C_ * O_) return;
    int o = id & (O_ - 1);
    int c = (id >> 6) & (C_ - 1);
    int k = id / (C_ * O_);
    wt[id] = w[(o * C_ + c) * K2_ + k];
}

// ---------------------------------------------------------------------------
// Kernel A: 3x3 conv -> 18 offset + 9 mask channels, fused coord calc.
// Round-3 arithmetic (proven), restructured: block = 256 thr = 64 px x 4
// c-groups (16 ch each), grid 2048 -> 8 blocks/CU. LDS reduce (stride-1,
// conflict-free). blockIdx&7 = batch -> XCD/L2 locality. c0 via
// readfirstlane -> weight chain provably uniform -> s_load.
// ---------------------------------------------------------------------------
__global__ __launch_bounds__(256, 6) void conv_offmask_k(
    const float* __restrict__ x,
    const float* __restrict__ w_off, const float* __restrict__ b_off,
    const float* __restrict__ w_mod, const float* __restrict__ b_mod,
    float* __restrict__ pyA, float* __restrict__ pxA, float* __restrict__ mA) {
    __shared__ float red[3 * 27 * 64];           // 20.7 KB

    int b     = blockIdx.x & 7;
    int strip = blockIdx.x >> 3;                 // 0..255
    int tid   = threadIdx.x;
    int px    = tid & 63;
    int cgrp  = tid >> 6;                        // 0..3 channel group
    int c0    = __builtin_amdgcn_readfirstlane(cgrp << 4);
    int p     = strip * 64 + px;
    int w     = p & (W_ - 1);
    int h     = p >> 7;

    int offs[9];
    float valid[9];
#pragma unroll
    for (int i = 0; i < 9; i++) {
        int dy = i / 3 - 1, dx = i % 3 - 1;
        int yy = h + dy, xx = w + dx;
        bool v = (yy >= 0 && yy < H_ && xx >= 0 && xx < W_);
        int yc = min(max(yy, 0), H_ - 1);
        int xc = min(max(xx, 0), W_ - 1);
        offs[i] = yc * W_ + xc;
        valid[i] = v ? 1.0f : 0.0f;
    }

    float acc[27];
#pragma unroll
    for (int o = 0; o < 27; o++) acc[o] = 0.0f;

    const float* xb = x + (b * C_ + c0) * HWSZ;

    for (int c = 0; c < 16; c++) {
        const float* xc = xb + c * HWSZ;
        float v[9];
#pragma unroll
        for (int i = 0; i < 9; i++) v[i] = xc[offs[i]] * valid[i];
        int cg = c0 + c;                         // SGPR + loop idx -> uniform
        const float* wo = w_off + cg * 9;
#pragma unroll
        for (int o = 0; o < 18; o++) {
#pragma unroll
            for (int k = 0; k < 9; k++) acc[o] += v[k] * wo[o * (C_ * 9) + k];
        }
        const float* wm = w_mod + cg * 9;
#pragma unroll
        for (int o = 0; o < 9; o++) {
#pragma unroll
            for (int k = 0; k < 9; k++) acc[18 + o] += v[k] * wm[o * (C_ * 9) + k];
        }
    }

    if (cgrp) {
        int base = (cgrp - 1) * 27 * 64;
#pragma unroll
        for (int o = 0; o < 27; o++) red[base + o * 64 + px] = acc[o];  // stride-1
    }
    __syncthreads();
    if (cgrp == 0) {
#pragma unroll
        for (int o = 0; o < 27; o++)
            acc[o] += red[o * 64 + px] + red[1728 + o * 64 + px] + red[3456 + o * 64 + px];
#pragma unroll
        for (int k = 0; k < 9; k++) {
            float dy = acc[2 * k]     + b_off[2 * k];
            float dx = acc[2 * k + 1] + b_off[2 * k + 1];
            float mm = acc[18 + k]    + b_mod[k];
            float mask = 2.0f / (1.0f + __expf(-mm));
            float py = dy + (float)h - 1.0f + (float)(k / 3);
            float pxv = dx + (float)w - 1.0f + (float)(k % 3);
            int idx = (b * 9 + k) * HWSZ + p;
            pyA[idx] = py;
            pxA[idx] = pxv;
            mA[idx] = mask;
        }
    }
}

// ---------------------------------------------------------------------------
// Kernel B: bilinear sample -> LDS fp32 tile -> per-group 16-output FMA.
// Block = 256 thr = 64 px x 4 groups; grid 2048 -> 8 blocks/CU.
// Per tap k: group g samples channels 16g..16g+15 of its pixel into
// S[px][68] (fp32, +4 pad; b128 at LDS width floor), barrier; then group g
// accumulates outputs o = 16g..16g+15 over all 64 channels from LDS with
// wave-uniform s_load weights; barrier. acc[16]/thread -> low VGPR, no
// cross-group reduce (groups own disjoint o). Coalesced epilogue.
// blockIdx&7 = batch -> XCD/L2 locality (x[b] = 4.2 MB ~ one XCD L2).
// ---------------------------------------------------------------------------
__global__ __launch_bounds__(256, 6) void sample_stage_k(
    const float* __restrict__ x,
    const float* __restrict__ pyA, const float* __restrict__ pxA,
    const float* __restrict__ mA, const float* __restrict__ wt,
    const float* __restrict__ bias, float* __restrict__ out) {
    __shared__ float S[64 * 68];                 // 17.4 KB

    int b    = blockIdx.x & 7;
    int grp  = blockIdx.x >> 3;                  // 0..255
    int p0   = grp * 64;
    int tid  = threadIdx.x;
    int px   = tid & 63;
    int g    = tid >> 6;                         // c-group for sampling, o-group for FMA
    int c0   = __builtin_amdgcn_readfirstlane(g << 4);
    int pix  = p0 + px;

    float acc[16];
#pragma unroll
    for (int o = 0; o < 16; o++) acc[o] = 0.0f;

    const float* xs = x + (b * C_ + c0) * HWSZ;  // sampler channels c0..c0+15

    for (int k = 0; k < 9; k++) {
        int pidx = (b * 9 + k) * HWSZ + pix;
        float py = pyA[pidx];
        float pxv = pxA[pidx];
        float mk = mA[pidx];

        float y0f = floorf(py), x0f = floorf(pxv);
        float wy = py - y0f, wx = pxv - x0f;
        int y0 = (int)y0f, x0 = (int)x0f;
        int y1 = y0 + 1, x1 = x0 + 1;
        float vy0 = (y0 >= 0 && y0 < H_) ? mk : 0.0f;   // fold mask
        float vy1 = (y1 >= 0 && y1 < H_) ? mk : 0.0f;
        float vx0 = (x0 >= 0 && x0 < W_) ? 1.0f : 0.0f;
        float vx1 = (x1 >= 0 && x1 < W_) ? 1.0f : 0.0f;
        int y0r = min(max(y0, 0), H_ - 1) * W_;
        int y1r = min(max(y1, 0), H_ - 1) * W_;
        int x0c = min(max(x0, 0), W_ - 1);
        int x1c = min(max(x1, 0), W_ - 1);

        float w00 = (1.0f - wy) * (1.0f - wx) * vy0 * vx0;
        float w01 = (1.0f - wy) * wx * vy0 * vx1;
        float w10 = wy * (1.0f - wx) * vy1 * vx0;
        float w11 = wy * wx * vy1 * vx1;

        int o00 = y0r + x0c, o01 = y0r + x1c;
        int o10 = y1r + x0c, o11 = y1r + x1c;

        // sample 16 channels -> 4x float4 LDS stores (16B aligned)
#pragma unroll
        for (int i = 0; i < 4; i++) {
            floatx4 sv;
#pragma unroll
            for (int j = 0; j < 4; j++) {
                const float* xc = xs + (i * 4 + j) * HWSZ;
                sv[j] = w00 * xc[o00] + w01 * xc[o01] + w10 * xc[o10] + w11 * xc[o11];
            }
            *(floatx4*)&S[px * 68 + c0 + i * 4] = sv;
        }

        __syncthreads();

        // FMA: outputs o = c0..c0+15 over all 64 channels from LDS
        const float* wk = wt + k * (C_ * O_) + c0;   // uniform -> s_load
#pragma unroll
        for (int c4 = 0; c4 < 16; c4++) {
            floatx4 sv = *(const floatx4*)&S[px * 68 + c4 * 4];
            const float* wp = wk + (c4 * 4) * O_;
#pragma unroll
            for (int j = 0; j < 4; j++)
#pragma unroll
                for (int oo = 0; oo < 16; oo++)
                    acc[oo] += sv[j] * wp[j * O_ + oo];
        }

        __syncthreads();
    }

    // Epilogue: group g stores o = c0..c0+15, coalesced over px
    int obase = (b * O_ + c0) * HWSZ + p0 + px;
#pragma unroll
    for (int oo = 0; oo < 16; oo++)
        out[obase + oo * HWSZ] = acc[oo] + bias[c0 + oo];
}

// ---------------------------------------------------------------------------
extern "C" void kernel_launch(void* const* d_in, const int* in_sizes, int n_in,
                              void* d_out, int out_size, void* d_ws, size_t ws_size,
                              hipStream_t stream) {
    const float* x     = (const float*)d_in[0];
    const float* w_off = (const float*)d_in[1];
    const float* b_off = (const float*)d_in[2];
    const float* w_mod = (const float*)d_in[3];
    const float* b_mod = (const float*)d_in[4];
    const float* w     = (const float*)d_in[5];
    const float* bias  = (const float*)d_in[6];
    float* out = (float*)d_out;

    const int nCoord = B_ * K2_ * HWSZ;          // 1,179,648
    float* pyA = (float*)d_ws;
    float* pxA = pyA + nCoord;
    float* mA  = pxA + nCoord;
    float* wt  = mA + nCoord;                    // 36,864 floats

    hipLaunchKernelGGL(transpose_w_k, dim3(144), dim3(256), 0, stream, w, wt);
    hipLaunchKernelGGL(conv_offmask_k, dim3(2048), dim3(256), 0, stream,
                       x, w_off, b_off, w_mod, b_mod, pyA, pxA, mA);
    hipLaunchKernelGGL(sample_stage_k, dim3(2048), dim3(256), 0, stream,
                       x, pyA, pxA, mA, wt, bias, out);
}